// Round 6
// baseline (6261.802 us; speedup 1.0000x reference)
//
#include <hip/hip_runtime.h>
#include <hip/hip_bf16.h>

typedef __hip_bfloat16 bf16;
typedef __attribute__((ext_vector_type(8))) short short8;
typedef __attribute__((ext_vector_type(4))) float float4v;

#define B_    1024
#define H_    512
#define G4H   2048
#define F_    32
#define CIN_  4
#define K_    30
#define STRIDE_ 6
#define L_    924
#define T_    150
#define KD_   40
#define NSTEPS_ 10
#define BH    (B_ * H_)
#define STRF  16   // ints between flags = 64B (one cacheline per flag)

__device__ __forceinline__ float sigmoidf_(float x) { return 1.f / (1.f + __expf(-x)); }
__device__ __forceinline__ float tanhf_(float x)    { return 1.f - 2.f / (__expf(2.f * x) + 1.f); }
__device__ __forceinline__ float b2f_(short s) {
    return __uint_as_float(((unsigned)(unsigned short)s) << 16);
}
__device__ __forceinline__ unsigned short f2bu_(float v) {
    union { __hip_bfloat16 b; unsigned short u; } cv;
    cv.b = __float2bfloat16(v);
    return cv.u;
}
// write-through (agent-scope) bf16 store: no dirty L2 line -> no wbl2 needed
__device__ __forceinline__ void stwt_(bf16* p, float v) {
    __hip_atomic_store((unsigned short*)p, f2bu_(v), __ATOMIC_RELAXED, __HIP_MEMORY_SCOPE_AGENT);
}

// ---------------------------------------------------------------------------
__global__ __launch_bounds__(256) void cvt_kernel(const float* __restrict__ src,
                                                  bf16* __restrict__ dst, int n) {
    int i = blockIdx.x * 256 + threadIdx.x;
    if (i < n) dst[i] = __float2bfloat16(src[i]);
}

__global__ void bias_kernel(const float* __restrict__ bih0, const float* __restrict__ bhh0,
                            const float* __restrict__ bih1, const float* __restrict__ bhh1,
                            float* __restrict__ b0, float* __restrict__ b1) {
    int i = blockIdx.x * 256 + threadIdx.x;
    if (i < G4H)      b0[i] = bih0[i] + bhh0[i];
    else if (i < 2*G4H) { int j = i - G4H; b1[j] = bih1[j] + bhh1[j]; }
}

// ---------------------------------------------------------------------------
__global__ __launch_bounds__(256) void conv_kernel(
    const float* __restrict__ x, const float* __restrict__ w,
    const float* __restrict__ cb, bf16* __restrict__ seq)
{
    __shared__ float w_lds[CIN_ * K_ * F_];
    __shared__ float x_lds[CIN_ * L_];
    int tid = threadIdx.x;
    int b = blockIdx.x;
    for (int i = tid; i < CIN_ * K_ * F_; i += 256) {
        int f = i & 31, r = i >> 5;
        w_lds[r * 32 + f] = w[f * (CIN_ * K_) + r];
    }
    const float* xb = x + (size_t)b * (CIN_ * L_);
    for (int i = tid; i < CIN_ * L_; i += 256)
        x_lds[i] = xb[i];
    __syncthreads();
    int f = tid & 31, tt = tid >> 5;
    float cbf = cb[f];
    for (int t0 = 0; t0 < T_; t0 += 8) {
        int t = t0 + tt;
        if (t < T_) {
            float acc = cbf;
            #pragma unroll
            for (int c = 0; c < CIN_; ++c) {
                const float* xr = x_lds + c * L_ + t * STRIDE_;
                const float* wr = w_lds + c * K_ * 32 + f;
                #pragma unroll
                for (int k = 0; k < K_; ++k)
                    acc += xr[k] * wr[k * 32];
            }
            acc = fmaxf(acc, 0.f);
            seq[(size_t)t * (B_ * F_) + b * F_ + f] = __float2bfloat16(acc);
        }
    }
}

// ---------------------------------------------------------------------------
// sync: padded per-block flags; release = barrier-drained stores + waitcnt +
// relaxed agent store. acquire = relaxed poll + buffer_inv (invalidate-only;
// clean lines dropped, dirty lines in the shared per-XCD L2 are preserved --
// which is what makes same-XCD plain-store handoff work).
// ---------------------------------------------------------------------------
__device__ __forceinline__ void wait2(const int* fa, int ta, const int* fb, int tb) {
    const int t = threadIdx.x;
    if (t < 64) {
        const int* p = nullptr; int tgt = 0;
        if (t < 32) { if (fa) { p = fa + t * STRF;        tgt = ta; } }
        else        { if (fb) { p = fb + (t - 32) * STRF; tgt = tb; } }
        for (;;) {
            int v = p ? __hip_atomic_load(p, __ATOMIC_RELAXED, __HIP_MEMORY_SCOPE_AGENT)
                      : 0x7fffffff;
            if (__all(v >= tgt)) break;
            __builtin_amdgcn_s_sleep(2);
        }
    }
    __syncthreads();
    __builtin_amdgcn_fence(__ATOMIC_ACQUIRE, "agent");   // buffer_inv
}

__device__ __forceinline__ void signal1(int* f, int val) {
    __syncthreads();                       // all waves' stores drained at barrier
    if (threadIdx.x == 0) {
        __builtin_amdgcn_s_waitcnt(0);     // own stores acked at coherent point
        __hip_atomic_store(f, val, __ATOMIC_RELAXED, __HIP_MEMORY_SCOPE_AGENT);
    }
}

// ---------------------------------------------------------------------------
// One layer step for (m0: 256 rows across 4 waves, 64 rows/wave) x
// (j0: 16 cols, 4 gates). Wih AND Whh LDS-resident. C state in registers.
//
// DEPTH-4 chunked register pipeline (the round-6 change): st[4][4][4] =
// 256 staging VGPRs, 64 x 16B loads in flight per wave (vs 2 chunks / 512B
// in rounds 4-5). Little's law: in-flight bytes set the latency-bound
// streaming rate for the 512KB/step A-reads; depth 2 -> ~35us/step observed.
// 256-thread shape (1 wave/SIMD, 1 block/CU) gives the 512-VGPR budget this
// needs; r5 compiled honestly (176 VGPR, no spill) under the same bounds.
// Spill tripwire: FETCH_SIZE must stay ~122MB.
//
// XCD-locality (r5, kept): Hprev is always a same-XCD buffer written with
// plain cached stores -> local-L2 hits. Cross-XCD data (h0 for L1) is
// written write-through via Hwt.
// ---------------------------------------------------------------------------
template<int P1KS, int XSTR, typename MW>
__device__ __forceinline__ void layer_step(
    const bf16* __restrict__ X, const bf16* __restrict__ Hprev,
    const short8* __restrict__ WldsH, const short8* __restrict__ WldsI,
    float bi, float bff, float bg, float bo,
    float (&creg)[16], bf16* __restrict__ Hwt, bf16* __restrict__ Hloc,
    int m0, int j0, int wid, int lane, MW&& midwait)
{
    const int row16 = lane & 15;
    const int quad  = lane >> 4;
    const int mrow  = m0 + wid * 64 + row16;

    constexpr int TOT = 16 + P1KS;       // k-groups (K=32 each), Hprev first
    constexpr int NC  = (TOT + 3) / 4;   // chunks of 4 groups

    const bf16* hb[4];
    const bf16* xb[4];
    #pragma unroll
    for (int q = 0; q < 4; ++q) {
        hb[q] = Hprev + (size_t)(mrow + q * 16) * H_ + quad * 8;
        xb[q] = X + (size_t)(mrow + q * 16) * XSTR + quad * 8;
    }

    float4v st[4][4][4];   // [chunk mod 4][group in chunk][row quarter]

    auto issue = [&](int c) {
        #pragma unroll
        for (int g = 0; g < 4; ++g) {
            int k = c * 4 + g;
            if (k < TOT) {
                #pragma unroll
                for (int q = 0; q < 4; ++q)
                    st[c & 3][g][q] = (k < 16)
                        ? *(const float4v*)(hb[q] + k * 32)
                        : *(const float4v*)(xb[q] + (k - 16) * 32);
            }
        }
        __builtin_amdgcn_sched_barrier(0);   // pin: loads may not sink below
    };
    auto ka = [&](int c) {
        #pragma unroll
        for (int g = 0; g < 4; ++g) {
            int k = c * 4 + g;
            if (k < TOT) {
                #pragma unroll
                for (int q = 0; q < 4; ++q)
                    asm volatile("" :: "v"(st[c & 3][g][q]));
            }
        }
    };

    issue(0);
    issue(1);
    issue(2);
    if (NC > 3) issue(3);
    midwait();              // L1: f0-wait polls here while h1 chunks land

    float4v acc[4][4];
    #pragma unroll
    for (int q = 0; q < 4; ++q)
        #pragma unroll
        for (int g = 0; g < 4; ++g)
            acc[q][g] = (float4v){0.f, 0.f, 0.f, 0.f};

    #pragma unroll
    for (int c = 0; c < NC; ++c) {
        ka(c);   // materialize chunk c (chunks c+1..c+3 stay in flight)
        #pragma unroll
        for (int g = 0; g < 4; ++g) {
            int k = c * 4 + g;
            if (k < TOT) {
                const short8* W = (k < 16) ? WldsH : WldsI;
                const int ks = (k < 16) ? k : (k - 16);
                short8 av[4];
                #pragma unroll
                for (int q = 0; q < 4; ++q)
                    av[q] = __builtin_bit_cast(short8, st[c & 3][g][q]);
                #pragma unroll
                for (int gg = 0; gg < 4; ++gg) {
                    short8 bfr = W[(ks * 4 + gg) * 64 + lane];
                    #pragma unroll
                    for (int q = 0; q < 4; ++q)
                        acc[q][gg] = __builtin_amdgcn_mfma_f32_16x16x32_bf16(av[q], bfr, acc[q][gg], 0, 0, 0);
                }
            }
        }
        if (c + 4 < NC) issue(c + 4);   // refill freed parity slot
    }

    // ---- epilogue: gates, c update, packed h store ----
    float hval[16];
    #pragma unroll
    for (int ms = 0; ms < 4; ++ms) {
        #pragma unroll
        for (int r = 0; r < 4; ++r) {
            float ig = sigmoidf_(acc[ms][0][r] + bi);
            float fg = sigmoidf_(acc[ms][1][r] + bff);
            float gg = tanhf_(acc[ms][2][r] + bg);
            float og = sigmoidf_(acc[ms][3][r] + bo);
            float cn = fg * creg[ms * 4 + r] + ig * gg;
            creg[ms * 4 + r] = cn;
            hval[ms * 4 + r] = og * tanhf_(cn);
        }
    }

    // butterfly pack: lanes l, l^1, l^2, l^3 hold the same row for a given
    // (ms,r) at 4 adjacent cols -> 8B chunks replicated in the 4-lane group,
    // each lane stores the 4 chunks with (i>>2) == (lane&3).
    unsigned wA[16];
    #pragma unroll
    for (int i = 0; i < 16; ++i) {
        float o = __shfl_xor(hval[i], 1);
        float lo = (lane & 1) ? o : hval[i];
        float hi = (lane & 1) ? hval[i] : o;
        wA[i] = (unsigned)f2bu_(lo) | ((unsigned)f2bu_(hi) << 16);
    }
    unsigned long long q[16];
    #pragma unroll
    for (int i = 0; i < 16; ++i) {
        unsigned o2 = __shfl_xor(wA[i], 2);
        q[i] = (lane & 2) ? (((unsigned long long)wA[i] << 32) | o2)
                          : (((unsigned long long)o2 << 32) | wA[i]);
    }
    const int cchunk = j0 + (row16 & ~3);
    #pragma unroll
    for (int i = 0; i < 16; ++i) {
        if ((i >> 2) == (lane & 3)) {
            int ms = i >> 2, r = i & 3;
            size_t off = (size_t)(m0 + wid * 64 + ms * 16 + quad * 4 + r) * H_ + cchunk;
            if (Hwt)
                __hip_atomic_store((unsigned long long*)(Hwt + off), q[i],
                                   __ATOMIC_RELAXED, __HIP_MEMORY_SCOPE_AGENT);
            if (Hloc)
                *(unsigned long long*)(Hloc + off) = q[i];
        }
    }
}

// ---------------------------------------------------------------------------
struct PP {
    const bf16 *seq, *Wih0, *Whh0, *Wih1, *Whh1, *dwb;
    const float *b0, *b1, *dec_b;
    float *fut;
    bf16 *h0, *h0loc, *h1, *y;   // h0/h0loc/h1: 3 slots of [B,H] each
    int *flags;                  // f0[128], f1[128], fy[128], 64B apart
};

// Persistent kernel, 256 blocks (1/CU), 256 threads (4 waves = 1/SIMD ->
// 512-VGPR budget). Swizzle: bid&7 = layer*4+mg puts each (layer,mg)
// 32-block peer group on ONE XCD (hardware round-robins bid%8 across XCDs):
//   - L0(mg) peers share h0loc reads -> local L2 (plain stores)
//   - L1(mg) peers share h1 reads    -> local L2 (plain stores, encoder)
//   - only h0 (L0 -> L1) crosses XCDs -> write-through copy
// flag value = t+1 after step t. 3 h-slots (slot = t%3). Waits:
//   L0(t): f0>=t   (peers' h0[t-1] ready + slot safety), f1>=t-2 (slot safety)
//   L1(t): f1>=t   (h1[t-1] + slot safety; h1 prefetch), f0>=t+1 (h0[t])
//   y-round s: f1>=T+s (h1[T-1+s] ready), f0>=T+s for s>=1 (y slot consumed)
__global__ __launch_bounds__(256, 1) void lstm_persist(PP P) {
    __shared__ short8 WldsH[4096];   // Whh slice, 64 KB
    __shared__ short8 WldsI[4096];   // Wih slice, 64 KB (L0 uses 256 entries)

    const int bid   = blockIdx.x;
    const int gsw   = bid & 7;
    const bool isL0 = (gsw < 4);
    const int mg    = gsw & 3;
    const int jj    = bid >> 3;
    const int lb    = mg * 32 + jj;       // logical id within layer
    const int j0    = jj * 16;
    const int m0    = mg * 256;
    const int tid   = threadIdx.x;
    const int wid   = tid >> 6;
    const int lane  = tid & 63;

    // stage weight slices into LDS (frag-major)
    {
        const bf16* Whh = isL0 ? P.Whh0 : P.Whh1;
        for (int i = 0; i < 16; ++i) {
            int s = tid + i * 256;
            int frag = s >> 6, ln = s & 63;
            int ks = frag >> 2, g = frag & 3;
            WldsH[s] = *(const short8*)(Whh + (size_t)(g * H_ + j0 + (ln & 15)) * H_
                                        + ks * 32 + (ln >> 4) * 8);
        }
        if (isL0) {
            int frag = tid >> 6, ln = tid & 63;
            int g = frag & 3;   // ks = 0
            WldsI[tid] = *(const short8*)(P.Wih0 + (size_t)(g * H_ + j0 + (ln & 15)) * F_
                                          + (ln >> 4) * 8);
        } else {
            for (int i = 0; i < 16; ++i) {
                int s = tid + i * 256;
                int frag = s >> 6, ln = s & 63;
                int ks = frag >> 2, g = frag & 3;
                WldsI[s] = *(const short8*)(P.Wih1 + (size_t)(g * H_ + j0 + (ln & 15)) * H_
                                            + ks * 32 + (ln >> 4) * 8);
            }
        }
        __syncthreads();
    }

    // loop-invariant per-thread bias values
    const float* bias = isL0 ? P.b0 : P.b1;
    const int jb  = j0 + (lane & 15);
    const float bi  = bias[jb];
    const float bff = bias[H_ + jb];
    const float bg  = bias[2 * H_ + jb];
    const float bo  = bias[3 * H_ + jb];

    float creg[16];
    #pragma unroll
    for (int i = 0; i < 16; ++i) creg[i] = 0.f;

    int* f0 = P.flags;
    int* f1 = P.flags + 128 * STRF;
    int* fy = P.flags + 256 * STRF;
    const int* f0g = f0 + mg * 32 * STRF;
    const int* f1g = f1 + mg * 32 * STRF;
    const int* fyg = fy + mg * 32 * STRF;

    auto noop = []{};

    if (isL0) {
        // encoder t = 0..149
        for (int t = 0; t < T_; ++t) {
            wait2(f0g, t, f1g, t - 2);
            layer_step<1, 32>(P.seq + (size_t)t * B_ * F_,
                              P.h0loc + (size_t)((t + 2) % 3) * BH, WldsH, WldsI,
                              bi, bff, bg, bo, creg,
                              P.h0 + (size_t)(t % 3) * BH,        // wt: for L1
                              P.h0loc + (size_t)(t % 3) * BH,     // loc: for us
                              m0, j0, wid, lane, noop);
            signal1(f0 + lb * STRF, t + 1);
        }
        // decoder: y-rounds interleaved with L0 steps
        for (int s = 0; s <= NSTEPS_; ++s) {
            wait2(f1g, T_ + s, (s >= 1) ? f0g : nullptr, T_ + s);
            {
                int id = lb * 256 + tid;        // b*32 + f
                int br = id >> 5, f = id & 31;
                const short8* hv = (const short8*)(P.h1 + (size_t)((T_ - 1 + s) % 3) * BH
                                                   + (size_t)br * H_);
                const short8* wv = (const short8*)(P.dwb + (size_t)f * H_);
                float acc = P.dec_b[f];
                for (int i = 0; i < H_ / 8; ++i) {
                    short8 h8 = hv[i], w8 = wv[i];
                    #pragma unroll
                    for (int k = 0; k < 8; ++k)
                        acc += b2f_(h8[k]) * b2f_(w8[k]);
                }
                stwt_(P.y + id, acc);
                if (s >= 1)
                    P.fut[(size_t)br * (F_ * NSTEPS_) + f * NSTEPS_ + (s - 1)] = acc;
            }
            signal1(fy + lb * STRF, s + 1);
            if (s < NSTEPS_) {
                int t = T_ + s;
                wait2(f0g, t, f1g, t - 2);
                wait2(fyg, s + 1, nullptr, 0);
                layer_step<1, 32>(P.y,
                                  P.h0loc + (size_t)((t + 2) % 3) * BH, WldsH, WldsI,
                                  bi, bff, bg, bo, creg,
                                  P.h0 + (size_t)(t % 3) * BH,
                                  P.h0loc + (size_t)(t % 3) * BH,
                                  m0, j0, wid, lane, noop);
                signal1(f0 + lb * STRF, t + 1);
            }
        }
    } else {
        // layer 1: t = 0..159. Split wait: f1 first (enables h1 prefetch),
        // f0 polled inside layer_step while h1 chunks are in flight.
        // h1 stores: plain cached (same-XCD consumers) until t >= T_-1,
        // then write-through (L0's cross-XCD y-round reads h1[T-1+s]).
        for (int t = 0; t < T_ + NSTEPS_; ++t) {
            wait2(f1g, t, nullptr, 0);
            bf16* hout = P.h1 + (size_t)(t % 3) * BH;
            bool wt = (t >= T_ - 1);
            layer_step<16, 512>(P.h0 + (size_t)(t % 3) * BH,
                                P.h1 + (size_t)((t + 2) % 3) * BH, WldsH, WldsI,
                                bi, bff, bg, bo, creg,
                                wt ? hout : nullptr,
                                wt ? nullptr : hout,
                                m0, j0, wid, lane,
                                [&]{ wait2(f0g, t + 1, nullptr, 0); });
            signal1(f1 + lb * STRF, t + 1);
        }
    }
}

// ---------------------------------------------------------------------------
__global__ __launch_bounds__(256) void deconv_kernel(
    const float* __restrict__ fut, const float* __restrict__ dw,
    float* __restrict__ out)
{
    int idx = blockIdx.x * 256 + threadIdx.x;
    if (idx >= B_ * 49) return;
    int b = idx / 49, jj = idx % 49;
    int tlo = jj - (KD_ - 1); if (tlo < 0) tlo = 0;
    int thi = jj; if (thi > NSTEPS_ - 1) thi = NSTEPS_ - 1;
    float acc = 0.f;
    for (int f = 0; f < F_; ++f) {
        const float* fr = fut + (size_t)b * (F_ * NSTEPS_) + f * NSTEPS_;
        const float* wr = dw + f * KD_;
        for (int t = tlo; t <= thi; ++t)
            acc += fr[t] * wr[jj - t];
    }
    out[idx] = acc;
}

// ---------------------------------------------------------------------------
extern "C" void kernel_launch(void* const* d_in, const int* in_sizes, int n_in,
                              void* d_out, int out_size, void* d_ws, size_t ws_size,
                              hipStream_t stream) {
    const float* x       = (const float*)d_in[0];
    const float* conv_w  = (const float*)d_in[1];
    const float* conv_b  = (const float*)d_in[2];
    const float* Wih0f   = (const float*)d_in[3];
    const float* Whh0f   = (const float*)d_in[4];
    const float* bih0    = (const float*)d_in[5];
    const float* bhh0    = (const float*)d_in[6];
    const float* Wih1f   = (const float*)d_in[7];
    const float* Whh1f   = (const float*)d_in[8];
    const float* bih1    = (const float*)d_in[9];
    const float* bhh1    = (const float*)d_in[10];
    const float* dec_wf  = (const float*)d_in[11];
    const float* dec_b   = (const float*)d_in[12];
    const float* deconvw = (const float*)d_in[13];
    float* out = (float*)d_out;

    char* ws = (char*)d_ws;
    size_t off = 0;
    auto alloc = [&](size_t bytes) { char* p = ws + off; off = (off + bytes + 255) & ~(size_t)255; return p; };
    bf16*  seq   = (bf16*) alloc((size_t)T_ * B_ * F_ * 2);
    float* b0v   = (float*)alloc(G4H * 4);
    float* b1v   = (float*)alloc(G4H * 4);
    bf16*  h0    = (bf16*) alloc((size_t)3 * BH * 2);
    bf16*  h0loc = (bf16*) alloc((size_t)3 * BH * 2);
    bf16*  h1    = (bf16*) alloc((size_t)3 * BH * 2);
    bf16*  y     = (bf16*) alloc((size_t)B_ * F_ * 2);
    float* fut   = (float*)alloc((size_t)B_ * F_ * NSTEPS_ * 4);
    bf16*  Wih0b = (bf16*) alloc((size_t)G4H * F_ * 2);
    bf16*  Whh0b = (bf16*) alloc((size_t)G4H * H_ * 2);
    bf16*  Wih1b = (bf16*) alloc((size_t)G4H * H_ * 2);
    bf16*  Whh1b = (bf16*) alloc((size_t)G4H * H_ * 2);
    bf16*  dec_wb= (bf16*) alloc((size_t)F_ * H_ * 2);
    int*   flags = (int*)  alloc(3 * 128 * STRF * 4);

    hipMemsetAsync(h0, 0, (size_t)3 * BH * 2, stream);
    hipMemsetAsync(h0loc, 0, (size_t)3 * BH * 2, stream);
    hipMemsetAsync(h1, 0, (size_t)3 * BH * 2, stream);
    hipMemsetAsync(flags, 0, 3 * 128 * STRF * 4, stream);

    cvt_kernel<<<(G4H * F_ + 255) / 256, 256, 0, stream>>>(Wih0f, Wih0b, G4H * F_);
    cvt_kernel<<<(G4H * H_ + 255) / 256, 256, 0, stream>>>(Whh0f, Whh0b, G4H * H_);
    cvt_kernel<<<(G4H * H_ + 255) / 256, 256, 0, stream>>>(Wih1f, Wih1b, G4H * H_);
    cvt_kernel<<<(G4H * H_ + 255) / 256, 256, 0, stream>>>(Whh1f, Whh1b, G4H * H_);
    cvt_kernel<<<(F_ * H_ + 255) / 256, 256, 0, stream>>>(dec_wf, dec_wb, F_ * H_);

    bias_kernel<<<16, 256, 0, stream>>>(bih0, bhh0, bih1, bhh1, b0v, b1v);
    conv_kernel<<<B_, 256, 0, stream>>>(x, conv_w, conv_b, seq);

    PP P;
    P.seq = seq; P.Wih0 = Wih0b; P.Whh0 = Whh0b; P.Wih1 = Wih1b; P.Whh1 = Whh1b;
    P.dwb = dec_wb; P.b0 = b0v; P.b1 = b1v; P.dec_b = dec_b;
    P.fut = fut; P.h0 = h0; P.h0loc = h0loc; P.h1 = h1; P.y = y;
    P.flags = flags;

    void* args[] = { &P };
    hipError_t err = hipLaunchCooperativeKernel((const void*)lstm_persist,
                                                dim3(256), dim3(256), args, 0, stream);
    if (err != hipSuccess) {
        lstm_persist<<<256, 256, 0, stream>>>(P);
    }

    deconv_kernel<<<196, 256, 0, stream>>>(fut, deconvw, out);
}

// Round 7
// 6040.197 us; speedup vs baseline: 1.0367x; 1.0367x over previous
//
#include <hip/hip_runtime.h>
#include <hip/hip_bf16.h>

typedef __hip_bfloat16 bf16;
typedef __attribute__((ext_vector_type(8))) short short8;
typedef __attribute__((ext_vector_type(4))) float float4v;

#define B_    1024
#define H_    512
#define G4H   2048
#define F_    32
#define CIN_  4
#define K_    30
#define STRIDE_ 6
#define L_    924
#define T_    150
#define KD_   40
#define NSTEPS_ 10
#define BH    (B_ * H_)
#define STRF  16   // ints between flags = 64B (one cacheline per flag)

__device__ __forceinline__ float sigmoidf_(float x) { return 1.f / (1.f + __expf(-x)); }
__device__ __forceinline__ float tanhf_(float x)    { return 1.f - 2.f / (__expf(2.f * x) + 1.f); }
__device__ __forceinline__ float b2f_(short s) {
    return __uint_as_float(((unsigned)(unsigned short)s) << 16);
}
__device__ __forceinline__ unsigned short f2bu_(float v) {
    union { __hip_bfloat16 b; unsigned short u; } cv;
    cv.b = __float2bfloat16(v);
    return cv.u;
}
// write-through (agent-scope) bf16 store: lands at the coherence point
__device__ __forceinline__ void stwt_(bf16* p, float v) {
    __hip_atomic_store((unsigned short*)p, f2bu_(v), __ATOMIC_RELAXED, __HIP_MEMORY_SCOPE_AGENT);
}
// L2-bypassing 16B load as 2x8B relaxed agent atomic loads. The flag-poll
// loop (relaxed agent loads, NO fence inside) only makes progress because
// such loads read the coherence point directly -- same mechanism here.
// Compiler tracks these in vmcnt normally, so the chunk pipeline works.
__device__ __forceinline__ float4v ldbp16_(const bf16* p) {
    const unsigned long long* q = (const unsigned long long*)p;
    union { unsigned long long u[2]; float4v v; } cv;
    cv.u[0] = __hip_atomic_load(q,     __ATOMIC_RELAXED, __HIP_MEMORY_SCOPE_AGENT);
    cv.u[1] = __hip_atomic_load(q + 1, __ATOMIC_RELAXED, __HIP_MEMORY_SCOPE_AGENT);
    return cv.v;
}

// ---------------------------------------------------------------------------
__global__ __launch_bounds__(256) void cvt_kernel(const float* __restrict__ src,
                                                  bf16* __restrict__ dst, int n) {
    int i = blockIdx.x * 256 + threadIdx.x;
    if (i < n) dst[i] = __float2bfloat16(src[i]);
}

__global__ void bias_kernel(const float* __restrict__ bih0, const float* __restrict__ bhh0,
                            const float* __restrict__ bih1, const float* __restrict__ bhh1,
                            float* __restrict__ b0, float* __restrict__ b1) {
    int i = blockIdx.x * 256 + threadIdx.x;
    if (i < G4H)      b0[i] = bih0[i] + bhh0[i];
    else if (i < 2*G4H) { int j = i - G4H; b1[j] = bih1[j] + bhh1[j]; }
}

// ---------------------------------------------------------------------------
__global__ __launch_bounds__(256) void conv_kernel(
    const float* __restrict__ x, const float* __restrict__ w,
    const float* __restrict__ cb, bf16* __restrict__ seq)
{
    __shared__ float w_lds[CIN_ * K_ * F_];
    __shared__ float x_lds[CIN_ * L_];
    int tid = threadIdx.x;
    int b = blockIdx.x;
    for (int i = tid; i < CIN_ * K_ * F_; i += 256) {
        int f = i & 31, r = i >> 5;
        w_lds[r * 32 + f] = w[f * (CIN_ * K_) + r];
    }
    const float* xb = x + (size_t)b * (CIN_ * L_);
    for (int i = tid; i < CIN_ * L_; i += 256)
        x_lds[i] = xb[i];
    __syncthreads();
    int f = tid & 31, tt = tid >> 5;
    float cbf = cb[f];
    for (int t0 = 0; t0 < T_; t0 += 8) {
        int t = t0 + tt;
        if (t < T_) {
            float acc = cbf;
            #pragma unroll
            for (int c = 0; c < CIN_; ++c) {
                const float* xr = x_lds + c * L_ + t * STRIDE_;
                const float* wr = w_lds + c * K_ * 32 + f;
                #pragma unroll
                for (int k = 0; k < K_; ++k)
                    acc += xr[k] * wr[k * 32];
            }
            acc = fmaxf(acc, 0.f);
            seq[(size_t)t * (B_ * F_) + b * F_ + f] = __float2bfloat16(acc);
        }
    }
}

// ---------------------------------------------------------------------------
// sync, FENCE-FREE steady state (the round-7 change):
// release = barrier-drained stores + waitcnt + relaxed agent flag store
// (unchanged). acquire = relaxed poll + __syncthreads ONLY -- the agent
// acquire fence (buffer_inv incl. L2 invalidate, issued per-wave, ~300x per
// step per XCD-L2 across the resident blocks) is DELETED. Freshness of
// consumed data comes from L2-bypassing loads (ldbp16_) instead of cache
// invalidation. __syncthreads provides the compiler memory barrier that
// keeps data loads from hoisting above the flag confirmation.
// ---------------------------------------------------------------------------
__device__ __forceinline__ void wait2(const int* fa, int ta, const int* fb, int tb) {
    const int t = threadIdx.x;
    if (t < 64) {
        const int* p = nullptr; int tgt = 0;
        if (t < 32) { if (fa) { p = fa + t * STRF;        tgt = ta; } }
        else        { if (fb) { p = fb + (t - 32) * STRF; tgt = tb; } }
        for (;;) {
            int v = p ? __hip_atomic_load(p, __ATOMIC_RELAXED, __HIP_MEMORY_SCOPE_AGENT)
                      : 0x7fffffff;
            if (__all(v >= tgt)) break;
            __builtin_amdgcn_s_sleep(2);
        }
    }
    __syncthreads();
}

__device__ __forceinline__ void signal1(int* f, int val) {
    __syncthreads();                       // all waves' stores drained at barrier
    if (threadIdx.x == 0) {
        __builtin_amdgcn_s_waitcnt(0);     // own stores acked at coherent point
        __hip_atomic_store(f, val, __ATOMIC_RELAXED, __HIP_MEMORY_SCOPE_AGENT);
    }
}

// ---------------------------------------------------------------------------
// One layer step for (m0: 256 rows across 4 waves, 64 rows/wave) x
// (j0: 16 cols, 4 gates). Wih AND Whh LDS-resident. C state in registers.
// Depth-2 chunked pinned prefetch (r5 structure, 176 VGPR, no spill).
// Hprev (k<16) is always inter-block h state -> L2-bypassing loads.
// X (k>=16): XBP=false -> plain cached (seq, pre-kernel data);
//            XBP=true  -> bypassing (h0 for L1, y for L0 decoder).
// Epilogue: shfl-butterfly packs 4 adjacent cols into 8B write-through
// agent-scope stores.
// ---------------------------------------------------------------------------
template<int P1KS, int XSTR, bool XBP, typename MW>
__device__ __forceinline__ void layer_step(
    const bf16* __restrict__ X, const bf16* __restrict__ Hprev,
    const short8* __restrict__ WldsH, const short8* __restrict__ WldsI,
    float bi, float bff, float bg, float bo,
    float (&creg)[16], bf16* __restrict__ Hout,
    int m0, int j0, int wid, int lane, MW&& midwait)
{
    const int row16 = lane & 15;
    const int quad  = lane >> 4;
    const int mrow  = m0 + wid * 64 + row16;

    constexpr int TOT = 16 + P1KS;       // k-groups (K=32 each), Hprev first
    constexpr int NC  = (TOT + 3) / 4;   // chunks of 4 groups

    const bf16* hb[4];
    const bf16* xb[4];
    #pragma unroll
    for (int q = 0; q < 4; ++q) {
        hb[q] = Hprev + (size_t)(mrow + q * 16) * H_ + quad * 8;
        xb[q] = X + (size_t)(mrow + q * 16) * XSTR + quad * 8;
    }

    float4v st[2][4][4];   // [chunk parity][group in chunk][row quarter]

    auto issue = [&](int c) {
        #pragma unroll
        for (int g = 0; g < 4; ++g) {
            int k = c * 4 + g;
            if (k < TOT) {
                #pragma unroll
                for (int q = 0; q < 4; ++q) {
                    if (k < 16)
                        st[c & 1][g][q] = ldbp16_(hb[q] + k * 32);
                    else if (XBP)
                        st[c & 1][g][q] = ldbp16_(xb[q] + (k - 16) * 32);
                    else
                        st[c & 1][g][q] = *(const float4v*)(xb[q] + (k - 16) * 32);
                }
            }
        }
        __builtin_amdgcn_sched_barrier(0);   // pin: loads may not sink below
    };
    auto ka = [&](int c) {
        #pragma unroll
        for (int g = 0; g < 4; ++g) {
            int k = c * 4 + g;
            if (k < TOT) {
                #pragma unroll
                for (int q = 0; q < 4; ++q)
                    asm volatile("" :: "v"(st[c & 1][g][q]));
            }
        }
    };

    issue(0);
    if (NC > 1) issue(1);
    midwait();              // L1: f0-wait polls here while h1 chunks land

    float4v acc[4][4];
    #pragma unroll
    for (int q = 0; q < 4; ++q)
        #pragma unroll
        for (int g = 0; g < 4; ++g)
            acc[q][g] = (float4v){0.f, 0.f, 0.f, 0.f};

    #pragma unroll
    for (int c = 0; c < NC; ++c) {
        ka(c);   // materialize chunk c (chunk c+1 stays in flight)
        #pragma unroll
        for (int g = 0; g < 4; ++g) {
            int k = c * 4 + g;
            if (k < TOT) {
                const short8* W = (k < 16) ? WldsH : WldsI;
                const int ks = (k < 16) ? k : (k - 16);
                short8 av[4];
                #pragma unroll
                for (int q = 0; q < 4; ++q)
                    av[q] = __builtin_bit_cast(short8, st[c & 1][g][q]);
                #pragma unroll
                for (int gg = 0; gg < 4; ++gg) {
                    short8 bfr = W[(ks * 4 + gg) * 64 + lane];
                    #pragma unroll
                    for (int q = 0; q < 4; ++q)
                        acc[q][gg] = __builtin_amdgcn_mfma_f32_16x16x32_bf16(av[q], bfr, acc[q][gg], 0, 0, 0);
                }
            }
        }
        if (c + 2 < NC) issue(c + 2);   // refill freed parity slot
    }

    // ---- epilogue: gates, c update, packed h store ----
    float hval[16];
    #pragma unroll
    for (int ms = 0; ms < 4; ++ms) {
        #pragma unroll
        for (int r = 0; r < 4; ++r) {
            float ig = sigmoidf_(acc[ms][0][r] + bi);
            float fg = sigmoidf_(acc[ms][1][r] + bff);
            float gg = tanhf_(acc[ms][2][r] + bg);
            float og = sigmoidf_(acc[ms][3][r] + bo);
            float cn = fg * creg[ms * 4 + r] + ig * gg;
            creg[ms * 4 + r] = cn;
            hval[ms * 4 + r] = og * tanhf_(cn);
        }
    }

    // butterfly pack: lanes l, l^1, l^2, l^3 hold the same row for a given
    // (ms,r) at 4 adjacent cols -> 8B chunks replicated in the 4-lane group,
    // each lane stores the 4 chunks with (i>>2) == (lane&3).
    unsigned wA[16];
    #pragma unroll
    for (int i = 0; i < 16; ++i) {
        float o = __shfl_xor(hval[i], 1);
        float lo = (lane & 1) ? o : hval[i];
        float hi = (lane & 1) ? hval[i] : o;
        wA[i] = (unsigned)f2bu_(lo) | ((unsigned)f2bu_(hi) << 16);
    }
    unsigned long long q[16];
    #pragma unroll
    for (int i = 0; i < 16; ++i) {
        unsigned o2 = __shfl_xor(wA[i], 2);
        q[i] = (lane & 2) ? (((unsigned long long)wA[i] << 32) | o2)
                          : (((unsigned long long)o2 << 32) | wA[i]);
    }
    const int cchunk = j0 + (row16 & ~3);
    #pragma unroll
    for (int i = 0; i < 16; ++i) {
        if ((i >> 2) == (lane & 3)) {
            int ms = i >> 2, r = i & 3;
            size_t off = (size_t)(m0 + wid * 64 + ms * 16 + quad * 4 + r) * H_ + cchunk;
            __hip_atomic_store((unsigned long long*)(Hout + off), q[i],
                               __ATOMIC_RELAXED, __HIP_MEMORY_SCOPE_AGENT);
        }
    }
}

// ---------------------------------------------------------------------------
struct PP {
    const bf16 *seq, *Wih0, *Whh0, *Wih1, *Whh1, *dwb;
    const float *b0, *b1, *dec_b;
    float *fut;
    bf16 *h0, *h1, *y;       // h0/h1: 3 slots of [B,H] each
    int *flags;              // f0[128], f1[128], fy[128], 64B apart
};

// Persistent kernel, 256 blocks (1/CU), 256 threads (4 waves = 1/SIMD ->
// 512-VGPR budget). Swizzle: bid&7 = layer*4+mg keeps each (layer,mg)
// 32-block peer group on one XCD (L3 locality; freshness no longer depends
// on it since all inter-block reads bypass L2).
// flag value = t+1 after step t. 3 h-slots (slot = t%3). Waits:
//   L0(t): f0>=t   (peers' h0[t-1] ready + slot safety), f1>=t-2 (slot safety)
//   L1(t): f1>=t   (h1[t-1] + slot safety; h1 prefetch), f0>=t+1 (h0[t])
//   y-round s: f1>=T+s (h1[T-1+s] ready), f0>=T+s for s>=1 (y slot consumed)
__global__ __launch_bounds__(256, 1) void lstm_persist(PP P) {
    __shared__ short8 WldsH[4096];   // Whh slice, 64 KB
    __shared__ short8 WldsI[4096];   // Wih slice, 64 KB (L0 uses 256 entries)

    const int bid   = blockIdx.x;
    const int gsw   = bid & 7;
    const bool isL0 = (gsw < 4);
    const int mg    = gsw & 3;
    const int jj    = bid >> 3;
    const int lb    = mg * 32 + jj;       // logical id within layer
    const int j0    = jj * 16;
    const int m0    = mg * 256;
    const int tid   = threadIdx.x;
    const int wid   = tid >> 6;
    const int lane  = tid & 63;

    // stage weight slices into LDS (frag-major)
    {
        const bf16* Whh = isL0 ? P.Whh0 : P.Whh1;
        for (int i = 0; i < 16; ++i) {
            int s = tid + i * 256;
            int frag = s >> 6, ln = s & 63;
            int ks = frag >> 2, g = frag & 3;
            WldsH[s] = *(const short8*)(Whh + (size_t)(g * H_ + j0 + (ln & 15)) * H_
                                        + ks * 32 + (ln >> 4) * 8);
        }
        if (isL0) {
            int frag = tid >> 6, ln = tid & 63;
            int g = frag & 3;   // ks = 0
            WldsI[tid] = *(const short8*)(P.Wih0 + (size_t)(g * H_ + j0 + (ln & 15)) * F_
                                          + (ln >> 4) * 8);
        } else {
            for (int i = 0; i < 16; ++i) {
                int s = tid + i * 256;
                int frag = s >> 6, ln = s & 63;
                int ks = frag >> 2, g = frag & 3;
                WldsI[s] = *(const short8*)(P.Wih1 + (size_t)(g * H_ + j0 + (ln & 15)) * H_
                                            + ks * 32 + (ln >> 4) * 8);
            }
        }
        __syncthreads();
    }

    // loop-invariant per-thread bias values
    const float* bias = isL0 ? P.b0 : P.b1;
    const int jb  = j0 + (lane & 15);
    const float bi  = bias[jb];
    const float bff = bias[H_ + jb];
    const float bg  = bias[2 * H_ + jb];
    const float bo  = bias[3 * H_ + jb];

    float creg[16];
    #pragma unroll
    for (int i = 0; i < 16; ++i) creg[i] = 0.f;

    int* f0 = P.flags;
    int* f1 = P.flags + 128 * STRF;
    int* fy = P.flags + 256 * STRF;
    const int* f0g = f0 + mg * 32 * STRF;
    const int* f1g = f1 + mg * 32 * STRF;
    const int* fyg = fy + mg * 32 * STRF;

    auto noop = []{};

    if (isL0) {
        // encoder t = 0..149
        for (int t = 0; t < T_; ++t) {
            wait2(f0g, t, f1g, t - 2);
            layer_step<1, 32, false>(P.seq + (size_t)t * B_ * F_,
                              P.h0 + (size_t)((t + 2) % 3) * BH, WldsH, WldsI,
                              bi, bff, bg, bo, creg,
                              P.h0 + (size_t)(t % 3) * BH,
                              m0, j0, wid, lane, noop);
            signal1(f0 + lb * STRF, t + 1);
        }
        // decoder: y-rounds interleaved with L0 steps
        for (int s = 0; s <= NSTEPS_; ++s) {
            wait2(f1g, T_ + s, (s >= 1) ? f0g : nullptr, T_ + s);
            {
                int id = lb * 256 + tid;        // b*32 + f
                int br = id >> 5, f = id & 31;
                const unsigned long long* hq =
                    (const unsigned long long*)(P.h1 + (size_t)((T_ - 1 + s) % 3) * BH
                                                + (size_t)br * H_);
                const short8* wv = (const short8*)(P.dwb + (size_t)f * H_);
                float acc = P.dec_b[f];
                for (int i = 0; i < H_ / 8; ++i) {
                    union { unsigned long long u[2]; short8 s; } hh;
                    hh.u[0] = __hip_atomic_load(hq + 2 * i,     __ATOMIC_RELAXED, __HIP_MEMORY_SCOPE_AGENT);
                    hh.u[1] = __hip_atomic_load(hq + 2 * i + 1, __ATOMIC_RELAXED, __HIP_MEMORY_SCOPE_AGENT);
                    short8 h8 = hh.s, w8 = wv[i];
                    #pragma unroll
                    for (int k = 0; k < 8; ++k)
                        acc += b2f_(h8[k]) * b2f_(w8[k]);
                }
                stwt_(P.y + id, acc);
                if (s >= 1)
                    P.fut[(size_t)br * (F_ * NSTEPS_) + f * NSTEPS_ + (s - 1)] = acc;
            }
            signal1(fy + lb * STRF, s + 1);
            if (s < NSTEPS_) {
                int t = T_ + s;
                wait2(f0g, t, f1g, t - 2);
                wait2(fyg, s + 1, nullptr, 0);
                layer_step<1, 32, true>(P.y,
                                  P.h0 + (size_t)((t + 2) % 3) * BH, WldsH, WldsI,
                                  bi, bff, bg, bo, creg,
                                  P.h0 + (size_t)(t % 3) * BH,
                                  m0, j0, wid, lane, noop);
                signal1(f0 + lb * STRF, t + 1);
            }
        }
    } else {
        // layer 1: t = 0..159. Split wait: f1 first (enables h1 prefetch),
        // f0 polled inside layer_step while h1 chunks are in flight.
        for (int t = 0; t < T_ + NSTEPS_; ++t) {
            wait2(f1g, t, nullptr, 0);
            layer_step<16, 512, true>(P.h0 + (size_t)(t % 3) * BH,
                                P.h1 + (size_t)((t + 2) % 3) * BH, WldsH, WldsI,
                                bi, bff, bg, bo, creg,
                                P.h1 + (size_t)(t % 3) * BH,
                                m0, j0, wid, lane,
                                [&]{ wait2(f0g, t + 1, nullptr, 0); });
            signal1(f1 + lb * STRF, t + 1);
        }
    }
}

// ---------------------------------------------------------------------------
__global__ __launch_bounds__(256) void deconv_kernel(
    const float* __restrict__ fut, const float* __restrict__ dw,
    float* __restrict__ out)
{
    int idx = blockIdx.x * 256 + threadIdx.x;
    if (idx >= B_ * 49) return;
    int b = idx / 49, jj = idx % 49;
    int tlo = jj - (KD_ - 1); if (tlo < 0) tlo = 0;
    int thi = jj; if (thi > NSTEPS_ - 1) thi = NSTEPS_ - 1;
    float acc = 0.f;
    for (int f = 0; f < F_; ++f) {
        const float* fr = fut + (size_t)b * (F_ * NSTEPS_) + f * NSTEPS_;
        const float* wr = dw + f * KD_;
        for (int t = tlo; t <= thi; ++t)
            acc += fr[t] * wr[jj - t];
    }
    out[idx] = acc;
}

// ---------------------------------------------------------------------------
extern "C" void kernel_launch(void* const* d_in, const int* in_sizes, int n_in,
                              void* d_out, int out_size, void* d_ws, size_t ws_size,
                              hipStream_t stream) {
    const float* x       = (const float*)d_in[0];
    const float* conv_w  = (const float*)d_in[1];
    const float* conv_b  = (const float*)d_in[2];
    const float* Wih0f   = (const float*)d_in[3];
    const float* Whh0f   = (const float*)d_in[4];
    const float* bih0    = (const float*)d_in[5];
    const float* bhh0    = (const float*)d_in[6];
    const float* Wih1f   = (const float*)d_in[7];
    const float* Whh1f   = (const float*)d_in[8];
    const float* bih1    = (const float*)d_in[9];
    const float* bhh1    = (const float*)d_in[10];
    const float* dec_wf  = (const float*)d_in[11];
    const float* dec_b   = (const float*)d_in[12];
    const float* deconvw = (const float*)d_in[13];
    float* out = (float*)d_out;

    char* ws = (char*)d_ws;
    size_t off = 0;
    auto alloc = [&](size_t bytes) { char* p = ws + off; off = (off + bytes + 255) & ~(size_t)255; return p; };
    bf16*  seq   = (bf16*) alloc((size_t)T_ * B_ * F_ * 2);
    float* b0v   = (float*)alloc(G4H * 4);
    float* b1v   = (float*)alloc(G4H * 4);
    bf16*  h0    = (bf16*) alloc((size_t)3 * BH * 2);
    bf16*  h1    = (bf16*) alloc((size_t)3 * BH * 2);
    bf16*  y     = (bf16*) alloc((size_t)B_ * F_ * 2);
    float* fut   = (float*)alloc((size_t)B_ * F_ * NSTEPS_ * 4);
    bf16*  Wih0b = (bf16*) alloc((size_t)G4H * F_ * 2);
    bf16*  Whh0b = (bf16*) alloc((size_t)G4H * H_ * 2);
    bf16*  Wih1b = (bf16*) alloc((size_t)G4H * H_ * 2);
    bf16*  Whh1b = (bf16*) alloc((size_t)G4H * H_ * 2);
    bf16*  dec_wb= (bf16*) alloc((size_t)F_ * H_ * 2);
    int*   flags = (int*)  alloc(3 * 128 * STRF * 4);

    hipMemsetAsync(h0, 0, (size_t)3 * BH * 2, stream);
    hipMemsetAsync(h1, 0, (size_t)3 * BH * 2, stream);
    hipMemsetAsync(flags, 0, 3 * 128 * STRF * 4, stream);

    cvt_kernel<<<(G4H * F_ + 255) / 256, 256, 0, stream>>>(Wih0f, Wih0b, G4H * F_);
    cvt_kernel<<<(G4H * H_ + 255) / 256, 256, 0, stream>>>(Whh0f, Whh0b, G4H * H_);
    cvt_kernel<<<(G4H * H_ + 255) / 256, 256, 0, stream>>>(Wih1f, Wih1b, G4H * H_);
    cvt_kernel<<<(G4H * H_ + 255) / 256, 256, 0, stream>>>(Whh1f, Whh1b, G4H * H_);
    cvt_kernel<<<(F_ * H_ + 255) / 256, 256, 0, stream>>>(dec_wf, dec_wb, F_ * H_);

    bias_kernel<<<16, 256, 0, stream>>>(bih0, bhh0, bih1, bhh1, b0v, b1v);
    conv_kernel<<<B_, 256, 0, stream>>>(x, conv_w, conv_b, seq);

    PP P;
    P.seq = seq; P.Wih0 = Wih0b; P.Whh0 = Whh0b; P.Wih1 = Wih1b; P.Whh1 = Whh1b;
    P.dwb = dec_wb; P.b0 = b0v; P.b1 = b1v; P.dec_b = dec_b;
    P.fut = fut; P.h0 = h0; P.h1 = h1; P.y = y;
    P.flags = flags;

    void* args[] = { &P };
    hipError_t err = hipLaunchCooperativeKernel((const void*)lstm_persist,
                                                dim3(256), dim3(256), args, 0, stream);
    if (err != hipSuccess) {
        lstm_persist<<<256, 256, 0, stream>>>(P);
    }

    deconv_kernel<<<196, 256, 0, stream>>>(fut, deconvw, out);
}

// Round 8
// 5012.536 us; speedup vs baseline: 1.2492x; 1.2050x over previous
//
#include <hip/hip_runtime.h>
#include <hip/hip_bf16.h>

typedef __hip_bfloat16 bf16;
typedef __attribute__((ext_vector_type(8))) short short8;
typedef __attribute__((ext_vector_type(4))) float float4v;

#define B_    1024
#define H_    512
#define G4H   2048
#define F_    32
#define CIN_  4
#define K_    30
#define STRIDE_ 6
#define L_    924
#define T_    150
#define KD_   40
#define NSTEPS_ 10
#define BH    (B_ * H_)
#define STRF  16   // ints between flags = 64B (one cacheline per flag)

__device__ __forceinline__ float sigmoidf_(float x) { return 1.f / (1.f + __expf(-x)); }
__device__ __forceinline__ float tanhf_(float x)    { return 1.f - 2.f / (__expf(2.f * x) + 1.f); }
__device__ __forceinline__ float b2f_(short s) {
    return __uint_as_float(((unsigned)(unsigned short)s) << 16);
}
__device__ __forceinline__ unsigned short f2bu_(float v) {
    union { __hip_bfloat16 b; unsigned short u; } cv;
    cv.b = __float2bfloat16(v);
    return cv.u;
}
// write-through (agent-scope) bf16 store: no dirty L2 line -> no wbl2 needed
__device__ __forceinline__ void stwt_(bf16* p, float v) {
    __hip_atomic_store((unsigned short*)p, f2bu_(v), __ATOMIC_RELAXED, __HIP_MEMORY_SCOPE_AGENT);
}

// ---------------------------------------------------------------------------
__global__ __launch_bounds__(256) void cvt_kernel(const float* __restrict__ src,
                                                  bf16* __restrict__ dst, int n) {
    int i = blockIdx.x * 256 + threadIdx.x;
    if (i < n) dst[i] = __float2bfloat16(src[i]);
}

__global__ void bias_kernel(const float* __restrict__ bih0, const float* __restrict__ bhh0,
                            const float* __restrict__ bih1, const float* __restrict__ bhh1,
                            float* __restrict__ b0, float* __restrict__ b1) {
    int i = blockIdx.x * 256 + threadIdx.x;
    if (i < G4H)      b0[i] = bih0[i] + bhh0[i];
    else if (i < 2*G4H) { int j = i - G4H; b1[j] = bih1[j] + bhh1[j]; }
}

// ---------------------------------------------------------------------------
__global__ __launch_bounds__(256) void conv_kernel(
    const float* __restrict__ x, const float* __restrict__ w,
    const float* __restrict__ cb, bf16* __restrict__ seq)
{
    __shared__ float w_lds[CIN_ * K_ * F_];
    __shared__ float x_lds[CIN_ * L_];
    int tid = threadIdx.x;
    int b = blockIdx.x;
    for (int i = tid; i < CIN_ * K_ * F_; i += 256) {
        int f = i & 31, r = i >> 5;
        w_lds[r * 32 + f] = w[f * (CIN_ * K_) + r];
    }
    const float* xb = x + (size_t)b * (CIN_ * L_);
    for (int i = tid; i < CIN_ * L_; i += 256)
        x_lds[i] = xb[i];
    __syncthreads();
    int f = tid & 31, tt = tid >> 5;
    float cbf = cb[f];
    for (int t0 = 0; t0 < T_; t0 += 8) {
        int t = t0 + tt;
        if (t < T_) {
            float acc = cbf;
            #pragma unroll
            for (int c = 0; c < CIN_; ++c) {
                const float* xr = x_lds + c * L_ + t * STRIDE_;
                const float* wr = w_lds + c * K_ * 32 + f;
                #pragma unroll
                for (int k = 0; k < K_; ++k)
                    acc += xr[k] * wr[k * 32];
            }
            acc = fmaxf(acc, 0.f);
            seq[(size_t)t * (B_ * F_) + b * F_ + f] = __float2bfloat16(acc);
        }
    }
}

// ---------------------------------------------------------------------------
// sync: padded per-block flags; release = barrier-drained stores + waitcnt +
// relaxed agent store (producers write through, so no L2 writeback needed).
// acquire = relaxed poll + buffer_inv (acquire fence, invalidate-only).
// (Round-0 baseline protocol, restored exactly: every alternative tested in
// r5-r7 -- locality stores, fence removal, L2-bypass reads -- was neutral.)
// ---------------------------------------------------------------------------
__device__ __forceinline__ void wait2(const int* fa, int ta, const int* fb, int tb) {
    const int t = threadIdx.x;
    if (t < 64) {
        const int* p = nullptr; int tgt = 0;
        if (t < 32) { if (fa) { p = fa + t * STRF;        tgt = ta; } }
        else        { if (fb) { p = fb + (t - 32) * STRF; tgt = tb; } }
        for (;;) {
            int v = p ? __hip_atomic_load(p, __ATOMIC_RELAXED, __HIP_MEMORY_SCOPE_AGENT)
                      : 0x7fffffff;
            if (__all(v >= tgt)) break;
            __builtin_amdgcn_s_sleep(2);
        }
    }
    __syncthreads();
    __builtin_amdgcn_fence(__ATOMIC_ACQUIRE, "agent");   // buffer_inv, no wbl2
}

__device__ __forceinline__ void signal1(int* f, int val) {
    __syncthreads();                       // all waves' stores drained at barrier
    if (threadIdx.x == 0) {
        __builtin_amdgcn_s_waitcnt(0);     // own stores acked at coherent point
        __hip_atomic_store(f, val, __ATOMIC_RELAXED, __HIP_MEMORY_SCOPE_AGENT);
    }
}

// ---------------------------------------------------------------------------
// One layer step for (m0: 256 rows) x (j0: 16 cols, 4 gates), 4 waves,
// 64 rows/wave. Wih AND Whh LDS-resident. C state in registers.
// ROUND-0 BASELINE inner loop: simple rolled k-loop, compiler-scheduled
// (every pinning/chunking/hoisting variant in r1-r6 was equal or worse;
// the sched_barrier variants regressed up to +1.7ms).
// Only deltas vs baseline: biases passed in (hoisted, r3+) and the
// butterfly-packed 8B write-through h stores (r3+-verified; 4x fewer store
// transactions on the serial path than 2B scalar).
// ---------------------------------------------------------------------------
template<int P1KS, int XSTR>
__device__ __forceinline__ void layer_step(
    const bf16* __restrict__ X, const bf16* __restrict__ Hprev,
    const short8* __restrict__ WldsH, const short8* __restrict__ WldsI,
    float bi, float bff, float bg, float bo,
    float (&creg)[16], bf16* __restrict__ Hout,
    int m0, int j0, int wid, int lane)
{
    const int row16 = lane & 15;
    const int quad  = lane >> 4;
    const int mrow  = m0 + wid * 64 + row16;

    float4v acc[4][4];
    #pragma unroll
    for (int ms = 0; ms < 4; ++ms)
        #pragma unroll
        for (int g = 0; g < 4; ++g)
            acc[ms][g] = (float4v){0.f, 0.f, 0.f, 0.f};

    // part 1: X @ Wih^T (B from LDS)
    for (int ks = 0; ks < P1KS; ++ks) {
        short8 av[4];
        #pragma unroll
        for (int ms = 0; ms < 4; ++ms)
            av[ms] = *(const short8*)(X + (size_t)(mrow + ms * 16) * XSTR
                                      + ks * 32 + quad * 8);
        #pragma unroll
        for (int g = 0; g < 4; ++g) {
            short8 bfr = WldsI[(ks * 4 + g) * 64 + lane];
            #pragma unroll
            for (int ms = 0; ms < 4; ++ms)
                acc[ms][g] = __builtin_amdgcn_mfma_f32_16x16x32_bf16(av[ms], bfr, acc[ms][g], 0, 0, 0);
        }
    }

    // part 2: Hprev @ Whh^T (B from LDS)
    for (int ks = 0; ks < 16; ++ks) {
        short8 av[4];
        #pragma unroll
        for (int ms = 0; ms < 4; ++ms)
            av[ms] = *(const short8*)(Hprev + (size_t)(mrow + ms * 16) * H_
                                      + ks * 32 + quad * 8);
        #pragma unroll
        for (int g = 0; g < 4; ++g) {
            short8 bfr = WldsH[(ks * 4 + g) * 64 + lane];
            #pragma unroll
            for (int ms = 0; ms < 4; ++ms)
                acc[ms][g] = __builtin_amdgcn_mfma_f32_16x16x32_bf16(av[ms], bfr, acc[ms][g], 0, 0, 0);
        }
    }

    // ---- epilogue: gates, c update, packed h store ----
    float hval[16];
    #pragma unroll
    for (int ms = 0; ms < 4; ++ms) {
        #pragma unroll
        for (int r = 0; r < 4; ++r) {
            float ig = sigmoidf_(acc[ms][0][r] + bi);
            float fg = sigmoidf_(acc[ms][1][r] + bff);
            float gg = tanhf_(acc[ms][2][r] + bg);
            float og = sigmoidf_(acc[ms][3][r] + bo);
            float cn = fg * creg[ms * 4 + r] + ig * gg;
            creg[ms * 4 + r] = cn;
            hval[ms * 4 + r] = og * tanhf_(cn);
        }
    }

    // butterfly pack: lanes l, l^1, l^2, l^3 hold the same row for a given
    // (ms,r) at 4 adjacent cols -> 8B chunks replicated in the 4-lane group,
    // each lane stores the 4 chunks with (i>>2) == (lane&3).
    unsigned wA[16];
    #pragma unroll
    for (int i = 0; i < 16; ++i) {
        float o = __shfl_xor(hval[i], 1);
        float lo = (lane & 1) ? o : hval[i];
        float hi = (lane & 1) ? hval[i] : o;
        wA[i] = (unsigned)f2bu_(lo) | ((unsigned)f2bu_(hi) << 16);
    }
    unsigned long long q[16];
    #pragma unroll
    for (int i = 0; i < 16; ++i) {
        unsigned o2 = __shfl_xor(wA[i], 2);
        q[i] = (lane & 2) ? (((unsigned long long)wA[i] << 32) | o2)
                          : (((unsigned long long)o2 << 32) | wA[i]);
    }
    const int cchunk = j0 + (row16 & ~3);
    #pragma unroll
    for (int i = 0; i < 16; ++i) {
        if ((i >> 2) == (lane & 3)) {
            int ms = i >> 2, r = i & 3;
            size_t off = (size_t)(m0 + wid * 64 + ms * 16 + quad * 4 + r) * H_ + cchunk;
            __hip_atomic_store((unsigned long long*)(Hout + off), q[i],
                               __ATOMIC_RELAXED, __HIP_MEMORY_SCOPE_AGENT);
        }
    }
}

// ---------------------------------------------------------------------------
struct PP {
    const bf16 *seq, *Wih0, *Whh0, *Wih1, *Whh1, *dwb;
    const float *b0, *b1, *dec_b;
    float *fut;
    bf16 *h0, *h1, *y;       // h0/h1: 3 slots of [B,H] each
    int *flags;              // f0[128], f1[128], fy[128], 64B apart
};

// Persistent kernel, 256 blocks (1/CU), 256 threads. Swizzle: bid = jj*8 +
// layer*4 + mg puts each (layer,mg) 32-block peer group (shares h-slice
// reads) on one XCD.
// flag value = t+1 after step t. 3 h-slots (slot = t%3). Waits:
//   L0(t): f0>=t   (peers' h0[t-1] ready + slot safety), f1>=t-2 (slot safety)
//   L1(t): f0>=t+1 (h0[t] ready), f1>=t (peers' h1[t-1] ready + slot safety)
//   y-round s: f1>=T+s (h1[T-1+s] ready), f0>=T+s for s>=1 (y slot consumed)
__global__ __launch_bounds__(256, 1) void lstm_persist(PP P) {
    __shared__ short8 WldsH[4096];   // Whh slice, 64 KB
    __shared__ short8 WldsI[4096];   // Wih slice, 64 KB (L0 uses 256 entries)

    const int bid   = blockIdx.x;
    const int gsw   = bid & 7;
    const bool isL0 = (gsw < 4);
    const int mg    = gsw & 3;
    const int jj    = bid >> 3;
    const int lb    = mg * 32 + jj;       // logical id within layer
    const int j0    = jj * 16;
    const int m0    = mg * 256;
    const int tid   = threadIdx.x;
    const int wid   = tid >> 6;
    const int lane  = tid & 63;

    // stage weight slices into LDS (frag-major)
    {
        const bf16* Whh = isL0 ? P.Whh0 : P.Whh1;
        for (int i = 0; i < 16; ++i) {
            int s = tid + i * 256;
            int frag = s >> 6, ln = s & 63;
            int ks = frag >> 2, g = frag & 3;
            WldsH[s] = *(const short8*)(Whh + (size_t)(g * H_ + j0 + (ln & 15)) * H_
                                        + ks * 32 + (ln >> 4) * 8);
        }
        if (isL0) {
            int frag = tid >> 6, ln = tid & 63;
            int g = frag & 3;   // ks = 0
            WldsI[tid] = *(const short8*)(P.Wih0 + (size_t)(g * H_ + j0 + (ln & 15)) * F_
                                          + (ln >> 4) * 8);
        } else {
            for (int i = 0; i < 16; ++i) {
                int s = tid + i * 256;
                int frag = s >> 6, ln = s & 63;
                int ks = frag >> 2, g = frag & 3;
                WldsI[s] = *(const short8*)(P.Wih1 + (size_t)(g * H_ + j0 + (ln & 15)) * H_
                                            + ks * 32 + (ln >> 4) * 8);
            }
        }
        __syncthreads();
    }

    // loop-invariant per-thread bias values (hoisted, r3+)
    const float* bias = isL0 ? P.b0 : P.b1;
    const int jb  = j0 + (lane & 15);
    const float bi  = bias[jb];
    const float bff = bias[H_ + jb];
    const float bg  = bias[2 * H_ + jb];
    const float bo  = bias[3 * H_ + jb];

    float creg[16];
    #pragma unroll
    for (int i = 0; i < 16; ++i) creg[i] = 0.f;

    int* f0 = P.flags;
    int* f1 = P.flags + 128 * STRF;
    int* fy = P.flags + 256 * STRF;
    const int* f0g = f0 + mg * 32 * STRF;
    const int* f1g = f1 + mg * 32 * STRF;
    const int* fyg = fy + mg * 32 * STRF;

    if (isL0) {
        // encoder t = 0..149
        for (int t = 0; t < T_; ++t) {
            wait2(f0g, t, f1g, t - 2);
            layer_step<1, 32>(P.seq + (size_t)t * B_ * F_,
                              P.h0 + (size_t)((t + 2) % 3) * BH, WldsH, WldsI,
                              bi, bff, bg, bo,
                              creg, P.h0 + (size_t)(t % 3) * BH, m0, j0, wid, lane);
            signal1(f0 + lb * STRF, t + 1);
        }
        // decoder: y-rounds interleaved with L0 steps
        for (int s = 0; s <= NSTEPS_; ++s) {
            wait2(f1g, T_ + s, (s >= 1) ? f0g : nullptr, T_ + s);
            {
                int id = lb * 256 + tid;        // b*32 + f
                int br = id >> 5, f = id & 31;
                const short8* hv = (const short8*)(P.h1 + (size_t)((T_ - 1 + s) % 3) * BH
                                                   + (size_t)br * H_);
                const short8* wv = (const short8*)(P.dwb + (size_t)f * H_);
                float acc = P.dec_b[f];
                for (int i = 0; i < H_ / 8; ++i) {
                    short8 h8 = hv[i], w8 = wv[i];
                    #pragma unroll
                    for (int k = 0; k < 8; ++k)
                        acc += b2f_(h8[k]) * b2f_(w8[k]);
                }
                stwt_(P.y + id, acc);
                if (s >= 1)
                    P.fut[(size_t)br * (F_ * NSTEPS_) + f * NSTEPS_ + (s - 1)] = acc;
            }
            signal1(fy + lb * STRF, s + 1);
            if (s < NSTEPS_) {
                int t = T_ + s;
                wait2(f0g, t, f1g, t - 2);
                wait2(fyg, s + 1, nullptr, 0);
                layer_step<1, 32>(P.y,
                                  P.h0 + (size_t)((t + 2) % 3) * BH, WldsH, WldsI,
                                  bi, bff, bg, bo,
                                  creg, P.h0 + (size_t)(t % 3) * BH, m0, j0, wid, lane);
                signal1(f0 + lb * STRF, t + 1);
            }
        }
    } else {
        // layer 1: t = 0..159
        for (int t = 0; t < T_ + NSTEPS_; ++t) {
            wait2(f0g, t + 1, f1g, t);
            layer_step<16, 512>(P.h0 + (size_t)(t % 3) * BH,
                                P.h1 + (size_t)((t + 2) % 3) * BH, WldsH, WldsI,
                                bi, bff, bg, bo,
                                creg, P.h1 + (size_t)(t % 3) * BH, m0, j0, wid, lane);
            signal1(f1 + lb * STRF, t + 1);
        }
    }
}

// ---------------------------------------------------------------------------
__global__ __launch_bounds__(256) void deconv_kernel(
    const float* __restrict__ fut, const float* __restrict__ dw,
    float* __restrict__ out)
{
    int idx = blockIdx.x * 256 + threadIdx.x;
    if (idx >= B_ * 49) return;
    int b = idx / 49, jj = idx % 49;
    int tlo = jj - (KD_ - 1); if (tlo < 0) tlo = 0;
    int thi = jj; if (thi > NSTEPS_ - 1) thi = NSTEPS_ - 1;
    float acc = 0.f;
    for (int f = 0; f < F_; ++f) {
        const float* fr = fut + (size_t)b * (F_ * NSTEPS_) + f * NSTEPS_;
        const float* wr = dw + f * KD_;
        for (int t = tlo; t <= thi; ++t)
            acc += fr[t] * wr[jj - t];
    }
    out[idx] = acc;
}

// ---------------------------------------------------------------------------
extern "C" void kernel_launch(void* const* d_in, const int* in_sizes, int n_in,
                              void* d_out, int out_size, void* d_ws, size_t ws_size,
                              hipStream_t stream) {
    const float* x       = (const float*)d_in[0];
    const float* conv_w  = (const float*)d_in[1];
    const float* conv_b  = (const float*)d_in[2];
    const float* Wih0f   = (const float*)d_in[3];
    const float* Whh0f   = (const float*)d_in[4];
    const float* bih0    = (const float*)d_in[5];
    const float* bhh0    = (const float*)d_in[6];
    const float* Wih1f   = (const float*)d_in[7];
    const float* Whh1f   = (const float*)d_in[8];
    const float* bih1    = (const float*)d_in[9];
    const float* bhh1    = (const float*)d_in[10];
    const float* dec_wf  = (const float*)d_in[11];
    const float* dec_b   = (const float*)d_in[12];
    const float* deconvw = (const float*)d_in[13];
    float* out = (float*)d_out;

    char* ws = (char*)d_ws;
    size_t off = 0;
    auto alloc = [&](size_t bytes) { char* p = ws + off; off = (off + bytes + 255) & ~(size_t)255; return p; };
    bf16*  seq   = (bf16*) alloc((size_t)T_ * B_ * F_ * 2);
    float* b0v   = (float*)alloc(G4H * 4);
    float* b1v   = (float*)alloc(G4H * 4);
    bf16*  h0    = (bf16*) alloc((size_t)3 * BH * 2);
    bf16*  h1    = (bf16*) alloc((size_t)3 * BH * 2);
    bf16*  y     = (bf16*) alloc((size_t)B_ * F_ * 2);
    float* fut   = (float*)alloc((size_t)B_ * F_ * NSTEPS_ * 4);
    bf16*  Wih0b = (bf16*) alloc((size_t)G4H * F_ * 2);
    bf16*  Whh0b = (bf16*) alloc((size_t)G4H * H_ * 2);
    bf16*  Wih1b = (bf16*) alloc((size_t)G4H * H_ * 2);
    bf16*  Whh1b = (bf16*) alloc((size_t)G4H * H_ * 2);
    bf16*  dec_wb= (bf16*) alloc((size_t)F_ * H_ * 2);
    int*   flags = (int*)  alloc(3 * 128 * STRF * 4);

    hipMemsetAsync(h0, 0, (size_t)3 * BH * 2, stream);
    hipMemsetAsync(h1, 0, (size_t)3 * BH * 2, stream);
    hipMemsetAsync(flags, 0, 3 * 128 * STRF * 4, stream);

    cvt_kernel<<<(G4H * F_ + 255) / 256, 256, 0, stream>>>(Wih0f, Wih0b, G4H * F_);
    cvt_kernel<<<(G4H * H_ + 255) / 256, 256, 0, stream>>>(Whh0f, Whh0b, G4H * H_);
    cvt_kernel<<<(G4H * H_ + 255) / 256, 256, 0, stream>>>(Wih1f, Wih1b, G4H * H_);
    cvt_kernel<<<(G4H * H_ + 255) / 256, 256, 0, stream>>>(Whh1f, Whh1b, G4H * H_);
    cvt_kernel<<<(F_ * H_ + 255) / 256, 256, 0, stream>>>(dec_wf, dec_wb, F_ * H_);

    bias_kernel<<<16, 256, 0, stream>>>(bih0, bhh0, bih1, bhh1, b0v, b1v);
    conv_kernel<<<B_, 256, 0, stream>>>(x, conv_w, conv_b, seq);

    PP P;
    P.seq = seq; P.Wih0 = Wih0b; P.Whh0 = Whh0b; P.Wih1 = Wih1b; P.Whh1 = Whh1b;
    P.dwb = dec_wb; P.b0 = b0v; P.b1 = b1v; P.dec_b = dec_b;
    P.fut = fut; P.h0 = h0; P.h1 = h1; P.y = y;
    P.flags = flags;

    void* args[] = { &P };
    hipError_t err = hipLaunchCooperativeKernel((const void*)lstm_persist,
                                                dim3(256), dim3(256), args, 0, stream);
    if (err != hipSuccess) {
        lstm_persist<<<256, 256, 0, stream>>>(P);
    }

    deconv_kernel<<<196, 256, 0, stream>>>(fut, deconvw, out);
}